// Round 1
// baseline (350.061 us; speedup 1.0000x reference)
//
#include <hip/hip_runtime.h>
#include <hip/hip_bf16.h>

#define BATCH 65536

typedef __bf16 bf16_t;
typedef __bf16 bf16x8 __attribute__((ext_vector_type(8)));
typedef float  f32x4  __attribute__((ext_vector_type(4)));

__device__ __forceinline__ f32x4 mfma16(bf16x8 a, bf16x8 b, f32x4 c) {
    return __builtin_amdgcn_mfma_f32_16x16x32_bf16(a, b, c, 0, 0, 0);
}

// element index into a 128-col bf16 LDS tile, XOR-swizzled on 16B chunks
__device__ __forceinline__ int swz128(int row, int col) {
    return row * 128 + ((((col >> 3) ^ (row & 7)) << 3) | (col & 7));
}

// ---------------------------------------------------------------------------
// Weight prep: convert f32 weights into pre-swizzled bf16 B-fragments.
// Fragment (nt,kt): lane l, elem j holds W[32*kt + 8*(l>>4) + j][16*nt + (l&15)]
// stored at dst[fragIdx*512 + l*8 + j].
// ---------------------------------------------------------------------------
struct PrepSrcs { const float* p[13]; };

__global__ __launch_bounds__(256) void prep_weights(PrepSrcs ps, bf16_t* __restrict__ dst) {
    const int SRC[15]  = {0,1,2,2,3,4,5,5,6,7,8,9,10,11,12};
    const int KTt[15]  = {4,4,4,4,4,4,4,4,4,4,1,4,4,4,4};
    const int KLIM[15] = {128,128,128,128,128,128,128,128,128,128,32,128,128,128,128};
    const int NLIM[15] = {128,128,128,128,128,128,128,128,32,32,128,128,128,78,78};
    const int STR[15]  = {128,128,128,128,128,128,128,128,32,32,128,128,128,78,78};
    const int RO[15]   = {0,0,0,128,0,0,0,128,0,0,0,0,0,0,0};
    const int BASE[16] = {0,32,64,96,128,160,192,224,256,264,272,280,312,344,364,384};

    int f = blockIdx.x;
    int ei = 0;
    while (ei < 14 && BASE[ei + 1] <= f) ei++;
    int lf = f - BASE[ei];
    int kt = lf % KTt[ei];
    int nt = lf / KTt[ei];
    const float* s = ps.p[SRC[ei]];
    int Klim = KLIM[ei], Nlim = NLIM[ei], str = STR[ei], ro = RO[ei];
    #pragma unroll
    for (int r2 = 0; r2 < 2; r2++) {
        int idx = threadIdx.x * 2 + r2;
        int l = idx >> 3, j = idx & 7;
        int row = 32 * kt + 8 * (l >> 4) + j;
        int col = 16 * nt + (l & 15);
        float v = (row < Klim && col < Nlim) ? s[(row + ro) * str + col] : 0.f;
        dst[f * 512 + idx] = (bf16_t)v;
    }
}

// ---------------------------------------------------------------------------
// conv0: XDIM=4 input conv, pure vector math. 16 elements/block, 8 cols/thread.
// ---------------------------------------------------------------------------
__global__ __launch_bounds__(256) void conv0_kernel(
    const float* __restrict__ x, const float* __restrict__ ea,
    const float* __restrict__ rw1, const float* __restrict__ rb1,
    const float* __restrict__ rw2, const float* __restrict__ rb2,
    const float* __restrict__ kw, bf16_t* __restrict__ hout)
{
    const int tid = threadIdx.x;
    const int el = tid >> 4;
    const int c0 = (tid & 15) * 8;
    const int e = blockIdx.x * 16 + el;
    const float* px = x + e * 16;

    float xv[4][4];
    #pragma unroll
    for (int n = 0; n < 4; n++) {
        float4 v = ((const float4*)px)[n];
        xv[n][0] = v.x; xv[n][1] = v.y; xv[n][2] = v.z; xv[n][3] = v.w;
    }
    float t[4][4];
    #pragma unroll
    for (int n = 0; n < 4; n++)
        #pragma unroll
        for (int k = 0; k < 4; k++) {
            float s = rb1[k];
            #pragma unroll
            for (int i = 0; i < 4; i++) s += xv[n][i] * rw1[i * 4 + k];
            t[n][k] = s;
        }
    float o[4][8], xd[4][8], xs[4][8];
    #pragma unroll
    for (int c = 0; c < 8; c++) {
        int col = c0 + c;
        #pragma unroll
        for (int n = 0; n < 4; n++) {
            float r = rb2[col];
            #pragma unroll
            for (int k = 0; k < 4; k++) r += t[n][k] * rw2[k * 128 + col];
            o[n][c] = r;
            float d = 0.f, s2 = 0.f;
            #pragma unroll
            for (int i = 0; i < 4; i++) {
                d  += xv[n][i] * kw[i * 128 + col];
                s2 += xv[n][i] * kw[(4 + i) * 128 + col];
            }
            xd[n][c] = d; xs[n][c] = s2;
        }
    }
    float eav[6][5];
    const float* pea = ea + e * 30;
    #pragma unroll
    for (int ed2 = 0; ed2 < 6; ed2++)
        #pragma unroll
        for (int i = 0; i < 5; i++) eav[ed2][i] = pea[ed2 * 5 + i];

    const int ESRC[6] = {0, 0, 1, 0, 1, 2};
    const int EDST[6] = {1, 2, 2, 3, 3, 3};
    #pragma unroll
    for (int c = 0; c < 8; c++) {
        int col = c0 + c;
        float k0 = kw[8 * 128 + col], k1 = kw[9 * 128 + col], k2 = kw[10 * 128 + col];
        float k3 = kw[11 * 128 + col], k4 = kw[12 * 128 + col];
        #pragma unroll
        for (int ed2 = 0; ed2 < 6; ed2++) {
            float et = eav[ed2][0] * k0 + eav[ed2][1] * k1 + eav[ed2][2] * k2 +
                       eav[ed2][3] * k3 + eav[ed2][4] * k4;
            float mm = xd[EDST[ed2]][c] + xs[ESRC[ed2]][c] + et;
            mm = fmaxf(mm, 0.01f * mm);
            o[EDST[ed2]][c] += mm;
        }
    }
    #pragma unroll
    for (int n = 0; n < 4; n++) {
        bf16x8 vout;
        #pragma unroll
        for (int c = 0; c < 8; c++) vout[c] = (bf16_t)o[n][c];
        *(bf16x8*)(hout + (e * 4 + n) * 128 + c0) = vout;
    }
}

// ---------------------------------------------------------------------------
// MFMA conv (HDIM=128 input). 32 elements (=128 rows) per block, 4 waves.
// In-place update of h. wf = 128 pre-swizzled frags: rw1|rw2|kw_dst|kw_src.
// ---------------------------------------------------------------------------
__global__ __launch_bounds__(256, 2) void conv_mfma(
    bf16_t* __restrict__ h, const float* __restrict__ ea,
    const bf16_t* __restrict__ wf, const float* __restrict__ kwfull,
    const float* __restrict__ rb1, const float* __restrict__ rb2)
{
    __shared__ __align__(16) bf16_t lh[128 * 128];
    __shared__ __align__(16) bf16_t lt[128 * 128];
    __shared__ __align__(16) float  lea[960];

    const int tid = threadIdx.x;
    const int e0 = blockIdx.x * 32;
    const int r0 = e0 * 4;

    #pragma unroll
    for (int i = 0; i < 8; i++) {
        int cid = i * 256 + tid; int row = cid >> 4; int ch = cid & 15;
        bf16x8 v = *(const bf16x8*)(h + (r0 + row) * 128 + ch * 8);
        *(bf16x8*)(lh + row * 128 + ((ch ^ (row & 7)) << 3)) = v;
    }
    if (tid < 240) ((float4*)lea)[tid] = ((const float4*)(ea + e0 * 30))[tid];
    __syncthreads();

    const int w = tid >> 6, lane = tid & 63, q = lane >> 4, lr = lane & 15;

    bf16x8 ah[2][4];
    #pragma unroll
    for (int mt = 0; mt < 2; mt++) {
        int row = 32 * w + 16 * mt + lr;
        #pragma unroll
        for (int kt = 0; kt < 4; kt++)
            ah[mt][kt] = *(const bf16x8*)(lh + row * 128 + (((4 * kt + q) ^ (row & 7)) << 3));
    }
    // Pass 1: T = h@rw1 + rb1
    f32x4 acc[2][8];
    #pragma unroll
    for (int nt = 0; nt < 8; nt++) {
        float b = rb1[16 * nt + lr];
        acc[0][nt] = (f32x4){b, b, b, b};
        acc[1][nt] = (f32x4){b, b, b, b};
    }
    #pragma unroll
    for (int nt = 0; nt < 8; nt++)
        #pragma unroll
        for (int kt = 0; kt < 4; kt++) {
            bf16x8 b = *(const bf16x8*)(wf + (nt * 4 + kt) * 512 + lane * 8);
            acc[0][nt] = mfma16(ah[0][kt], b, acc[0][nt]);
            acc[1][nt] = mfma16(ah[1][kt], b, acc[1][nt]);
        }
    #pragma unroll
    for (int mt = 0; mt < 2; mt++)
        #pragma unroll
        for (int nt = 0; nt < 8; nt++)
            #pragma unroll
            for (int j = 0; j < 4; j++) {
                int row = 32 * w + 16 * mt + 4 * q + j;
                lt[swz128(row, 16 * nt + lr)] = (bf16_t)acc[mt][nt][j];
            }
    __syncthreads();

    bf16x8 at[2][4];
    #pragma unroll
    for (int mt = 0; mt < 2; mt++) {
        int row = 32 * w + 16 * mt + lr;
        #pragma unroll
        for (int kt = 0; kt < 4; kt++)
            at[mt][kt] = *(const bf16x8*)(lt + row * 128 + (((4 * kt + q) ^ (row & 7)) << 3));
    }
    const bf16_t* wf2 = wf + 32 * 512;
    const bf16_t* wfd = wf + 64 * 512;
    const bf16_t* wfs = wf + 96 * 512;

    for (int nt = 0; nt < 8; nt++) {
        int col = 16 * nt + lr;
        float b2v = rb2[col];
        f32x4 rr[2], kd[2], ks[2];
        rr[0] = (f32x4){b2v, b2v, b2v, b2v}; rr[1] = rr[0];
        kd[0] = (f32x4){0.f, 0.f, 0.f, 0.f}; kd[1] = kd[0];
        ks[0] = kd[0]; ks[1] = kd[0];
        #pragma unroll
        for (int kt = 0; kt < 4; kt++) {
            bf16x8 bw2 = *(const bf16x8*)(wf2 + (nt * 4 + kt) * 512 + lane * 8);
            bf16x8 bwd = *(const bf16x8*)(wfd + (nt * 4 + kt) * 512 + lane * 8);
            bf16x8 bws = *(const bf16x8*)(wfs + (nt * 4 + kt) * 512 + lane * 8);
            #pragma unroll
            for (int mt = 0; mt < 2; mt++) {
                rr[mt] = mfma16(at[mt][kt], bw2, rr[mt]);
                kd[mt] = mfma16(ah[mt][kt], bwd, kd[mt]);
                ks[mt] = mfma16(ah[mt][kt], bws, ks[mt]);
            }
        }
        float kwe0 = kwfull[256 * 128 + col], kwe1 = kwfull[257 * 128 + col];
        float kwe2 = kwfull[258 * 128 + col], kwe3 = kwfull[259 * 128 + col];
        float kwe4 = kwfull[260 * 128 + col];
        #pragma unroll
        for (int mt = 0; mt < 2; mt++) {
            int el = 8 * w + 4 * mt + q;
            const float* pe = lea + el * 30;
            float o0 = rr[mt][0], o1 = rr[mt][1], o2 = rr[mt][2], o3 = rr[mt][3];
            float mm;
            // edges: src {0,0,1,0,1,2}  dst {1,2,2,3,3,3}
            mm = kd[mt][1] + ks[mt][0] + (pe[0]*kwe0 + pe[1]*kwe1 + pe[2]*kwe2 + pe[3]*kwe3 + pe[4]*kwe4);
            mm = fmaxf(mm, 0.01f * mm); o1 += mm;
            mm = kd[mt][2] + ks[mt][0] + (pe[5]*kwe0 + pe[6]*kwe1 + pe[7]*kwe2 + pe[8]*kwe3 + pe[9]*kwe4);
            mm = fmaxf(mm, 0.01f * mm); o2 += mm;
            mm = kd[mt][2] + ks[mt][1] + (pe[10]*kwe0 + pe[11]*kwe1 + pe[12]*kwe2 + pe[13]*kwe3 + pe[14]*kwe4);
            mm = fmaxf(mm, 0.01f * mm); o2 += mm;
            mm = kd[mt][3] + ks[mt][0] + (pe[15]*kwe0 + pe[16]*kwe1 + pe[17]*kwe2 + pe[18]*kwe3 + pe[19]*kwe4);
            mm = fmaxf(mm, 0.01f * mm); o3 += mm;
            mm = kd[mt][3] + ks[mt][1] + (pe[20]*kwe0 + pe[21]*kwe1 + pe[22]*kwe2 + pe[23]*kwe3 + pe[24]*kwe4);
            mm = fmaxf(mm, 0.01f * mm); o3 += mm;
            mm = kd[mt][3] + ks[mt][2] + (pe[25]*kwe0 + pe[26]*kwe1 + pe[27]*kwe2 + pe[28]*kwe3 + pe[29]*kwe4);
            mm = fmaxf(mm, 0.01f * mm); o3 += mm;
            int gr = (e0 + el) * 4;
            h[(gr + 0) * 128 + col] = (bf16_t)o0;
            h[(gr + 1) * 128 + col] = (bf16_t)o1;
            h[(gr + 2) * 128 + col] = (bf16_t)o2;
            h[(gr + 3) * 128 + col] = (bf16_t)o3;
        }
    }
}

// ---------------------------------------------------------------------------
// Decoder + loss. 128 elements per block, 4 waves. Partial sums to ws.
// ---------------------------------------------------------------------------
__device__ __forceinline__ float ce_group(const float* p, const float* a, int off, int len) {
    float m = p[off];
    #pragma unroll
    for (int i = 1; i < 5; i++) if (i < len) m = fmaxf(m, p[off + i]);
    float am = a[off]; int lbl = 0;
    #pragma unroll
    for (int i = 1; i < 5; i++) if (i < len) { float av = a[off + i]; if (av > am) { am = av; lbl = i; } }
    float s = 0.f;
    #pragma unroll
    for (int i = 0; i < 5; i++) if (i < len) s += __expf(p[off + i] - m);
    return (m + __logf(s)) - p[off + lbl];
}

__global__ __launch_bounds__(256, 2) void decoder_kernel(
    const bf16_t* __restrict__ h, const float* __restrict__ eps,
    const float* __restrict__ arch, const bf16_t* __restrict__ wsw,
    const float* __restrict__ fc3_b, const float* __restrict__ fc4_b,
    const float* __restrict__ fc5_b, const float* __restrict__ d1_mb,
    const float* __restrict__ d1_rb, const float* __restrict__ d2_mb,
    const float* __restrict__ d2_rb,
    float* __restrict__ ce_part, float* __restrict__ kld_part)
{
    __shared__ __align__(16) unsigned char sm[73728];
    bf16_t* lA    = (bf16_t*)sm;             // 32 KB: hg, later Hg
    bf16_t* lz    = (bf16_t*)(sm + 32768);   // 8 KB: z
    bf16_t* lB    = (bf16_t*)(sm + 40960);   // 32 KB: h1d
    float*  lpred = (float*)sm;              // 40 KB: pred (aliases lA+lz)
    float*  lred  = (float*)(sm + 40960);    // reduce scratch (aliases lB)

    const int tid = threadIdx.x;
    const int e0 = blockIdx.x * 128;

    // hg = sum over 4 node rows
    #pragma unroll
    for (int i = 0; i < 8; i++) {
        int cid = i * 256 + tid; int el = cid >> 4; int ch = cid & 15;
        const bf16_t* gp = h + (e0 + el) * 512 + ch * 8;
        float s[8];
        #pragma unroll
        for (int k = 0; k < 8; k++) s[k] = 0.f;
        #pragma unroll
        for (int n = 0; n < 4; n++) {
            bf16x8 v = *(const bf16x8*)(gp + n * 128);
            #pragma unroll
            for (int k = 0; k < 8; k++) s[k] += (float)v[k];
        }
        bf16x8 ov;
        #pragma unroll
        for (int k = 0; k < 8; k++) ov[k] = (bf16_t)s[k];
        *(bf16x8*)(lA + el * 128 + ((ch ^ (el & 7)) << 3)) = ov;
    }
    __syncthreads();

    const int w = tid >> 6, lane = tid & 63, q = lane >> 4, lr = lane & 15;

    // GEMM1: [mu|lv] = hg @ [fc3|fc4] + b
    bf16x8 ag[2][4];
    #pragma unroll
    for (int mt = 0; mt < 2; mt++) {
        int row = 32 * w + 16 * mt + lr;
        #pragma unroll
        for (int kt = 0; kt < 4; kt++)
            ag[mt][kt] = *(const bf16x8*)(lA + row * 128 + (((4 * kt + q) ^ (row & 7)) << 3));
    }
    f32x4 acc1[2][4];
    #pragma unroll
    for (int nt = 0; nt < 4; nt++) {
        float b = (nt < 2) ? fc3_b[16 * nt + lr] : fc4_b[16 * (nt - 2) + lr];
        acc1[0][nt] = (f32x4){b, b, b, b};
        acc1[1][nt] = (f32x4){b, b, b, b};
    }
    const bf16_t* wfc = wsw + 256 * 512;
    #pragma unroll
    for (int nt = 0; nt < 4; nt++)
        #pragma unroll
        for (int kt = 0; kt < 4; kt++) {
            bf16x8 b = *(const bf16x8*)(wfc + (nt * 4 + kt) * 512 + lane * 8);
            acc1[0][nt] = mfma16(ag[0][kt], b, acc1[0][nt]);
            acc1[1][nt] = mfma16(ag[1][kt], b, acc1[1][nt]);
        }
    // z + kld partial
    float kldp = 0.f;
    #pragma unroll
    for (int mt = 0; mt < 2; mt++)
        #pragma unroll
        for (int n2 = 0; n2 < 2; n2++)
            #pragma unroll
            for (int j = 0; j < 4; j++) {
                float mu = acc1[mt][n2][j];
                float lv = acc1[mt][n2 + 2][j];
                kldp += 1.f + lv - mu * mu - __expf(lv);
                int row = 32 * w + 16 * mt + 4 * q + j;
                int k = 16 * n2 + lr;
                float zz = eps[(e0 + row) * 32 + k] * 0.01f * __expf(0.5f * lv) + mu;
                lz[row * 32 + ((((k >> 3) ^ (row & 3)) << 3) | (k & 7))] = (bf16_t)zz;
            }
    __syncthreads();

    // GEMM2: Hg = tanh(z @ fc5 + b)   (K=32)
    bf16x8 az[2];
    #pragma unroll
    for (int mt = 0; mt < 2; mt++) {
        int row = 32 * w + 16 * mt + lr;
        az[mt] = *(const bf16x8*)(lz + row * 32 + ((q ^ (row & 3)) << 3));
    }
    const bf16_t* wf5 = wsw + 272 * 512;
    f32x4 acc2[2][8];
    #pragma unroll
    for (int nt = 0; nt < 8; nt++) {
        float b = fc5_b[16 * nt + lr];
        acc2[0][nt] = (f32x4){b, b, b, b};
        acc2[1][nt] = (f32x4){b, b, b, b};
        bf16x8 bw = *(const bf16x8*)(wf5 + nt * 512 + lane * 8);
        acc2[0][nt] = mfma16(az[0], bw, acc2[0][nt]);
        acc2[1][nt] = mfma16(az[1], bw, acc2[1][nt]);
    }
    // write Hg over lA (all lA reads completed before previous barrier)
    #pragma unroll
    for (int mt = 0; mt < 2; mt++)
        #pragma unroll
        for (int nt = 0; nt < 8; nt++)
            #pragma unroll
            for (int j = 0; j < 4; j++) {
                float v = acc2[mt][nt][j];
                float ex = __expf(2.f * v);
                float th = 1.f - 2.f / (ex + 1.f);
                int row = 32 * w + 16 * mt + 4 * q + j;
                lA[swz128(row, 16 * nt + lr)] = (bf16_t)th;
            }
    __syncthreads();

    // GEMM3: h1d = lrelu(Hg@d1_mw+mb) + (Hg@d1_rw+rb)
    bf16x8 aH[2][4];
    #pragma unroll
    for (int mt = 0; mt < 2; mt++) {
        int row = 32 * w + 16 * mt + lr;
        #pragma unroll
        for (int kt = 0; kt < 4; kt++)
            aH[mt][kt] = *(const bf16x8*)(lA + row * 128 + (((4 * kt + q) ^ (row & 7)) << 3));
    }
    const bf16_t* wd1m = wsw + 280 * 512;
    const bf16_t* wd1r = wsw + 312 * 512;
    for (int nt = 0; nt < 8; nt++) {
        int col = 16 * nt + lr;
        float bm = d1_mb[col], br = d1_rb[col];
        f32x4 am[2], ar2[2];
        am[0] = (f32x4){bm, bm, bm, bm}; am[1] = am[0];
        ar2[0] = (f32x4){br, br, br, br}; ar2[1] = ar2[0];
        #pragma unroll
        for (int kt = 0; kt < 4; kt++) {
            bf16x8 b1 = *(const bf16x8*)(wd1m + (nt * 4 + kt) * 512 + lane * 8);
            bf16x8 b2 = *(const bf16x8*)(wd1r + (nt * 4 + kt) * 512 + lane * 8);
            #pragma unroll
            for (int mt = 0; mt < 2; mt++) {
                am[mt] = mfma16(aH[mt][kt], b1, am[mt]);
                ar2[mt] = mfma16(aH[mt][kt], b2, ar2[mt]);
            }
        }
        #pragma unroll
        for (int mt = 0; mt < 2; mt++)
            #pragma unroll
            for (int j = 0; j < 4; j++) {
                float v = fmaxf(am[mt][j], 0.01f * am[mt][j]) + ar2[mt][j];
                int row = 32 * w + 16 * mt + 4 * q + j;
                lB[swz128(row, col)] = (bf16_t)v;
            }
    }
    __syncthreads();

    // GEMM4: pred = lrelu(h1d@d2_mw+mb) + (h1d@d2_rw+rb), N=78 padded to 80
    bf16x8 a1[2][4];
    #pragma unroll
    for (int mt = 0; mt < 2; mt++) {
        int row = 32 * w + 16 * mt + lr;
        #pragma unroll
        for (int kt = 0; kt < 4; kt++)
            a1[mt][kt] = *(const bf16x8*)(lB + row * 128 + (((4 * kt + q) ^ (row & 7)) << 3));
    }
    const bf16_t* wd2m = wsw + 344 * 512;
    const bf16_t* wd2r = wsw + 364 * 512;
    for (int nt = 0; nt < 5; nt++) {
        int col = 16 * nt + lr;
        float bm = (col < 78) ? d2_mb[col] : 0.f;
        float br = (col < 78) ? d2_rb[col] : 0.f;
        f32x4 pm[2], pr[2];
        pm[0] = (f32x4){bm, bm, bm, bm}; pm[1] = pm[0];
        pr[0] = (f32x4){br, br, br, br}; pr[1] = pr[0];
        #pragma unroll
        for (int kt = 0; kt < 4; kt++) {
            bf16x8 b1 = *(const bf16x8*)(wd2m + (nt * 4 + kt) * 512 + lane * 8);
            bf16x8 b2 = *(const bf16x8*)(wd2r + (nt * 4 + kt) * 512 + lane * 8);
            #pragma unroll
            for (int mt = 0; mt < 2; mt++) {
                pm[mt] = mfma16(a1[mt][kt], b1, pm[mt]);
                pr[mt] = mfma16(a1[mt][kt], b2, pr[mt]);
            }
        }
        #pragma unroll
        for (int mt = 0; mt < 2; mt++)
            #pragma unroll
            for (int j = 0; j < 4; j++) {
                float v = fmaxf(pm[mt][j], 0.01f * pm[mt][j]) + pr[mt][j];
                int row = 32 * w + 16 * mt + 4 * q + j;
                lpred[row * 80 + col] = v;
            }
    }
    __syncthreads();

    // loss: 128 elems x 6 edge-slots = 768 tasks
    float ces = 0.f;
    for (int t3 = 0; t3 < 3; t3++) {
        int task = t3 * 256 + tid;
        int el = task / 6, u = task - el * 6;
        const float* pa = arch + ((e0 + el) * 6 + u) * 13;
        const float* pp = lpred + el * 80 + u * 13;
        ces += ce_group(pp, pa, 0, 4);
        ces += ce_group(pp, pa, 4, 4);
        ces += ce_group(pp, pa, 8, 5);
    }
    __syncthreads();
    lred[tid] = ces;
    __syncthreads();
    for (int s2 = 128; s2 > 0; s2 >>= 1) {
        if (tid < s2) lred[tid] += lred[tid + s2];
        __syncthreads();
    }
    if (tid == 0) ce_part[blockIdx.x] = lred[0];
    __syncthreads();
    lred[tid] = kldp;
    __syncthreads();
    for (int s2 = 128; s2 > 0; s2 >>= 1) {
        if (tid < s2) lred[tid] += lred[tid + s2];
        __syncthreads();
    }
    if (tid == 0) kld_part[blockIdx.x] = lred[0];
}

__global__ __launch_bounds__(256) void final_reduce(
    const float* __restrict__ ce_part, const float* __restrict__ kld_part,
    float* __restrict__ out)
{
    __shared__ float r[256];
    int tid = threadIdx.x;
    float c = 0.f, k = 0.f;
    for (int i = tid; i < 512; i += 256) { c += ce_part[i]; k += kld_part[i]; }
    r[tid] = c; __syncthreads();
    for (int s = 128; s > 0; s >>= 1) { if (tid < s) r[tid] += r[tid + s]; __syncthreads(); }
    float ctot = r[0];
    __syncthreads();
    r[tid] = k; __syncthreads();
    for (int s = 128; s > 0; s >>= 1) { if (tid < s) r[tid] += r[tid + s]; __syncthreads(); }
    if (tid == 0) {
        float ktot = r[0];
        out[0] = ctot / (65536.f * 6.f) - 0.5f * 0.005f * (ktot / (65536.f * 32.f));
    }
}

// ---------------------------------------------------------------------------
extern "C" void kernel_launch(void* const* d_in, const int* in_sizes, int n_in,
                              void* d_out, int out_size, void* d_ws, size_t ws_size,
                              hipStream_t stream)
{
    const float* x      = (const float*)d_in[0];
    const float* ea     = (const float*)d_in[1];
    const float* arch   = (const float*)d_in[2];
    const float* eps    = (const float*)d_in[3];
    const float* c0_rw1 = (const float*)d_in[5];
    const float* c0_rb1 = (const float*)d_in[6];
    const float* c0_rw2 = (const float*)d_in[7];
    const float* c0_rb2 = (const float*)d_in[8];
    const float* c0_kw  = (const float*)d_in[9];
    const float* c1_rw1 = (const float*)d_in[10];
    const float* c1_rb1 = (const float*)d_in[11];
    const float* c1_rw2 = (const float*)d_in[12];
    const float* c1_rb2 = (const float*)d_in[13];
    const float* c1_kw  = (const float*)d_in[14];
    const float* c2_rw1 = (const float*)d_in[15];
    const float* c2_rb1 = (const float*)d_in[16];
    const float* c2_rw2 = (const float*)d_in[17];
    const float* c2_rb2 = (const float*)d_in[18];
    const float* c2_kw  = (const float*)d_in[19];
    const float* fc3_w  = (const float*)d_in[20];
    const float* fc3_b  = (const float*)d_in[21];
    const float* fc4_w  = (const float*)d_in[22];
    const float* fc4_b  = (const float*)d_in[23];
    const float* fc5_w  = (const float*)d_in[24];
    const float* fc5_b  = (const float*)d_in[25];
    const float* d1_mw  = (const float*)d_in[26];
    const float* d1_mb  = (const float*)d_in[27];
    const float* d1_rw  = (const float*)d_in[28];
    const float* d1_rb  = (const float*)d_in[29];
    const float* d2_mw  = (const float*)d_in[30];
    const float* d2_mb  = (const float*)d_in[31];
    const float* d2_rw  = (const float*)d_in[32];
    const float* d2_rb  = (const float*)d_in[33];

    const size_t H_BYTES = (size_t)BATCH * 4 * 128 * 2;   // 67108864
    const size_t W_OFF   = H_BYTES;
    const size_t W_BYTES = (size_t)384 * 512 * 2;          // 393216
    const size_t P_OFF   = W_OFF + W_BYTES;

    bf16_t* hbuf   = (bf16_t*)d_ws;
    bf16_t* wsw    = (bf16_t*)((char*)d_ws + W_OFF);
    float* ce_part = (float*)((char*)d_ws + P_OFF);
    float* kld_part = ce_part + 512;

    PrepSrcs ps;
    ps.p[0] = c1_rw1; ps.p[1] = c1_rw2; ps.p[2] = c1_kw;
    ps.p[3] = c2_rw1; ps.p[4] = c2_rw2; ps.p[5] = c2_kw;
    ps.p[6] = fc3_w;  ps.p[7] = fc4_w;  ps.p[8] = fc5_w;
    ps.p[9] = d1_mw;  ps.p[10] = d1_rw; ps.p[11] = d2_mw; ps.p[12] = d2_rw;

    prep_weights<<<384, 256, 0, stream>>>(ps, wsw);
    conv0_kernel<<<BATCH / 16, 256, 0, stream>>>(x, ea, c0_rw1, c0_rb1, c0_rw2, c0_rb2, c0_kw, hbuf);
    conv_mfma<<<BATCH / 32, 256, 0, stream>>>(hbuf, ea, wsw, c1_kw, c1_rb1, c1_rb2);
    conv_mfma<<<BATCH / 32, 256, 0, stream>>>(hbuf, ea, wsw + 128 * 512, c2_kw, c2_rb1, c2_rb2);
    decoder_kernel<<<BATCH / 128, 256, 0, stream>>>(hbuf, eps, arch, wsw,
                                                    fc3_b, fc4_b, fc5_b, d1_mb, d1_rb, d2_mb, d2_rb,
                                                    ce_part, kld_part);
    final_reduce<<<1, 256, 0, stream>>>(ce_part, kld_part, (float*)d_out);
}